// Round 1
// 1224.532 us; speedup vs baseline: 1.8656x; 1.8656x over previous
//
#include <hip/hip_runtime.h>
#include <math.h>

// ---------------- problem constants ----------------
#define S_LEN   2048
#define BATCH   2
#define HDIM    1024
#define NH      16
#define NKV     4
#define HD      64
#define NE      16
#define FFN_D   2048
#define TOKENS  4096        // S*B
#define QKV_OUT 1536        // (NH + 2*NKV)*HD
#define CAP     640         // ceil(TOKENS*2/16*1.25)
#define CAP1    641
#define NSLOT   8192        // TOKENS*2
#define CHUNK   64          // MoE capacity-row chunk (small-ws path)

// ---------------- workspace layout (float elements) ----------------
#define OFF_SMALL 0UL                 // 24,576 floats: exp_idx, pos (int), gate
#define OFF_A     24576UL             // 4,194,304  (16 MB)
#define OFF_B     4218880UL           // 10,502,144 (40 MB); first 6,291,456 = qkv
#define OFF_C     14721024UL          // h1: full 21,004,288 (84 MB) or chunked 2,097,152 (8 MB)
#define FLOATS_BIG   35725312UL
#define FLOATS_SMALL 16818176UL

typedef __attribute__((ext_vector_type(8))) __bf16 bf16x8;
typedef __attribute__((ext_vector_type(4))) float f32x4;

__device__ __forceinline__ float gelu_tanh(float x) {
    float x3 = x * x * x;
    return 0.5f * x * (1.0f + tanhf(0.7978845608028654f * (x + 0.044715f * x3)));
}

// split fp32 -> (hi, lo) bf16 pair by truncation; x = hi + lo + O(2^-16 |x|)
__device__ __forceinline__ void split4(float4 v, ushort4& h, ushort4& l) {
    unsigned ux = __float_as_uint(v.x), uy = __float_as_uint(v.y);
    unsigned uz = __float_as_uint(v.z), uw = __float_as_uint(v.w);
    h = make_ushort4((unsigned short)(ux >> 16), (unsigned short)(uy >> 16),
                     (unsigned short)(uz >> 16), (unsigned short)(uw >> 16));
    float dx = v.x - __uint_as_float(ux & 0xFFFF0000u);
    float dy = v.y - __uint_as_float(uy & 0xFFFF0000u);
    float dz = v.z - __uint_as_float(uz & 0xFFFF0000u);
    float dw = v.w - __uint_as_float(uw & 0xFFFF0000u);
    l = make_ushort4((unsigned short)(__float_as_uint(dx) >> 16),
                     (unsigned short)(__float_as_uint(dy) >> 16),
                     (unsigned short)(__float_as_uint(dz) >> 16),
                     (unsigned short)(__float_as_uint(dw) >> 16));
}

// ---------------- LayerNorm: one block per token row ----------------
__global__ __launch_bounds__(256) void ln_kernel(const float* __restrict__ x,
                                                 const float* __restrict__ w,
                                                 const float* __restrict__ b,
                                                 float* __restrict__ y) {
    int row = blockIdx.x;
    int tid = threadIdx.x;
    const float4* xr = (const float4*)(x + (size_t)row * HDIM);
    float4 v = xr[tid];
    float sum = v.x + v.y + v.z + v.w;
    float sq  = v.x*v.x + v.y*v.y + v.z*v.z + v.w*v.w;
    __shared__ float s1[256], s2[256];
    s1[tid] = sum; s2[tid] = sq;
    __syncthreads();
    for (int off = 128; off > 0; off >>= 1) {
        if (tid < off) { s1[tid] += s1[tid + off]; s2[tid] += s2[tid + off]; }
        __syncthreads();
    }
    float mu  = s1[0] * (1.0f / HDIM);
    float var = s2[0] * (1.0f / HDIM) - mu * mu;
    float rs  = rsqrtf(var + 1e-5f);
    float4 w4 = ((const float4*)w)[tid];
    float4 b4 = ((const float4*)b)[tid];
    float4 o;
    o.x = (v.x - mu) * rs * w4.x + b4.x;
    o.y = (v.y - mu) * rs * w4.y + b4.y;
    o.z = (v.z - mu) * rs * w4.z + b4.z;
    o.w = (v.w - mu) * rs * w4.w + b4.w;
    ((float4*)(y + (size_t)row * HDIM))[tid] = o;
}

// ---------------- MFMA split-bf16 GEMM: C[z] = A[z] @ B[z]^T ----------------
// fp32 accuracy via 3-term bf16 split: Ah*Bh + Al*Bh + Ah*Bl.
// 128x128 tile, 4 waves (each a 64x64 quadrant of 4x4 16x16x32 fragments),
// BK=32. Reg-staged fp32->split->LDS; rows padded to 40 bf16 (80 B) to break
// the b128 8-way bank conflict of a 64 B stride. Next-tile global loads are
// issued before the MFMA block (latency hidden under compute).
#define BM  128
#define BN  128
#define BK  32
#define PAD 8
#define LDK (BK + PAD)   // 40 bf16 = 80 B per row (16B-aligned)

__global__ __launch_bounds__(256) void gemm_mfma(const float* __restrict__ A,
                                                 const float* __restrict__ B,
                                                 float* __restrict__ C,
                                                 const float* __restrict__ resid,
                                                 int M, int N, int K,
                                                 long long sA, long long sB, long long sC,
                                                 int act) {
    __shared__ __align__(16) unsigned short Ah[BM * LDK];
    __shared__ __align__(16) unsigned short Al[BM * LDK];
    __shared__ __align__(16) unsigned short Bh[BN * LDK];
    __shared__ __align__(16) unsigned short Bl[BN * LDK];

    int z = blockIdx.z;
    const float* Ab = A + (long long)z * sA;
    const float* Bb = B + (long long)z * sB;
    float* Cb = C + (long long)z * sC;
    int bm = blockIdx.y << 7;
    int bn = blockIdx.x << 7;

    int t    = threadIdx.x;
    int lane = t & 63;
    int w    = t >> 6;
    // staging coords: 8 threads per 32-fp32 row, 32 rows per pass, 4 passes
    int sr = t >> 3;          // 0..31
    int sc = (t & 7) << 2;    // fp32 col 0,4,...,28
    // fragment coords
    int fr = lane & 15;
    int fo = lane >> 4;       // 0..3
    int k0 = fo << 3;         // bf16 k-offset 0,8,16,24
    int wr = (w >> 1) << 6;   // wave row quadrant 0/64
    int wc = (w & 1) << 6;    // wave col quadrant 0/64

    f32x4 acc[4][4];
    #pragma unroll
    for (int m = 0; m < 4; ++m)
        #pragma unroll
        for (int n = 0; n < 4; ++n)
            acc[m][n] = (f32x4){0.f, 0.f, 0.f, 0.f};

    float4 ra[4], rb[4];
    // initial tile load (kt = 0)
    #pragma unroll
    for (int p = 0; p < 4; ++p) {
        int arow = bm + (p << 5) + sr; if (arow > M - 1) arow = M - 1;
        ra[p] = *(const float4*)(Ab + (long long)arow * K + sc);
        rb[p] = *(const float4*)(Bb + (long long)(bn + (p << 5) + sr) * K + sc);
    }

    for (int kt = 0; kt < K; kt += BK) {
        __syncthreads();   // previous compute's ds_reads complete
        #pragma unroll
        for (int p = 0; p < 4; ++p) {
            int r = (p << 5) + sr;
            ushort4 h, l;
            split4(ra[p], h, l);
            *(ushort4*)&Ah[r * LDK + sc] = h;
            *(ushort4*)&Al[r * LDK + sc] = l;
            split4(rb[p], h, l);
            *(ushort4*)&Bh[r * LDK + sc] = h;
            *(ushort4*)&Bl[r * LDK + sc] = l;
        }
        __syncthreads();

        // prefetch next K-tile into regs (consumed only after next barrier)
        if (kt + BK < K) {
            int kn = kt + BK;
            #pragma unroll
            for (int p = 0; p < 4; ++p) {
                int arow = bm + (p << 5) + sr; if (arow > M - 1) arow = M - 1;
                ra[p] = *(const float4*)(Ab + (long long)arow * K + kn + sc);
                rb[p] = *(const float4*)(Bb + (long long)(bn + (p << 5) + sr) * K + kn + sc);
            }
        }

        bf16x8 ahf[4], alf[4];
        #pragma unroll
        for (int m = 0; m < 4; ++m) {
            int ro = (wr + (m << 4) + fr) * LDK + k0;
            ahf[m] = *reinterpret_cast<const bf16x8*>(&Ah[ro]);
            alf[m] = *reinterpret_cast<const bf16x8*>(&Al[ro]);
        }
        #pragma unroll
        for (int n = 0; n < 4; ++n) {
            int ro = (wc + (n << 4) + fr) * LDK + k0;
            bf16x8 bhf = *reinterpret_cast<const bf16x8*>(&Bh[ro]);
            bf16x8 blf = *reinterpret_cast<const bf16x8*>(&Bl[ro]);
            #pragma unroll
            for (int m = 0; m < 4; ++m) {
                acc[m][n] = __builtin_amdgcn_mfma_f32_16x16x32_bf16(ahf[m], bhf, acc[m][n], 0, 0, 0);
                acc[m][n] = __builtin_amdgcn_mfma_f32_16x16x32_bf16(alf[m], bhf, acc[m][n], 0, 0, 0);
                acc[m][n] = __builtin_amdgcn_mfma_f32_16x16x32_bf16(ahf[m], blf, acc[m][n], 0, 0, 0);
            }
        }
    }

    // epilogue: C/D layout col = lane&15, row = (lane>>4)*4 + reg
    #pragma unroll
    for (int m = 0; m < 4; ++m) {
        int row0 = bm + wr + (m << 4) + (fo << 2);
        #pragma unroll
        for (int r = 0; r < 4; ++r) {
            int row = row0 + r;
            if (row >= M) continue;
            #pragma unroll
            for (int n = 0; n < 4; ++n) {
                float val = acc[m][n][r];
                if (act == 1) val = gelu_tanh(val);
                int col = bn + wc + (n << 4) + fr;
                long long off = (long long)row * N + col;
                if (resid) val += resid[(long long)z * sC + off];
                Cb[off] = val;
            }
        }
    }
}

// ---------------- tiled causal GQA flash attention ----------------
__global__ __launch_bounds__(256) void attn_tile_kernel(const float* __restrict__ qkv,
                                                        float* __restrict__ attn_out) {
    int bid = blockIdx.x;
    int h   = bid & 15;
    int b   = (bid >> 4) & 1;
    int qt  = bid >> 5;             // 0..31
    int q0  = qt << 6;
    int kvh = h >> 2;
    int t   = threadIdx.x;
    int tx  = t & 15, ty = t >> 4;  // 4x4 micro-tile coords

    __shared__ __align__(16) float Qs[64 * 68];   // [d][q], pre-scaled
    __shared__ __align__(16) float KPs[64 * 68];  // K as [d][k]; then P as [k][q]
    __shared__ __align__(16) float Vs[64 * 68];   // [k][d]

    int r  = t >> 2;                // staging row 0..63
    int d0 = (t & 3) << 4;          // staging dim offset 0,16,32,48

    {
        const float* qrow = qkv + ((size_t)(q0 + r) * BATCH + b) * QKV_OUT + h * HD + d0;
        #pragma unroll
        for (int u = 0; u < 16; u += 4) {
            float4 v = *(const float4*)(qrow + u);
            Qs[(d0 + u + 0) * 68 + r] = v.x * 0.125f;
            Qs[(d0 + u + 1) * 68 + r] = v.y * 0.125f;
            Qs[(d0 + u + 2) * 68 + r] = v.z * 0.125f;
            Qs[(d0 + u + 3) * 68 + r] = v.w * 0.125f;
        }
    }

    float m[4], l[4], o[4][4];
    #pragma unroll
    for (int i = 0; i < 4; ++i) {
        m[i] = -INFINITY; l[i] = 0.f;
        o[i][0] = o[i][1] = o[i][2] = o[i][3] = 0.f;
    }

    const float* kgbase = qkv + 1024 + kvh * HD;
    const float* vgbase = qkv + 1280 + kvh * HD;

    for (int c = 0; c <= q0; c += 64) {
        __syncthreads();
        {
            const float* krow = kgbase + ((size_t)(c + r) * BATCH + b) * QKV_OUT + d0;
            #pragma unroll
            for (int u = 0; u < 16; u += 4) {
                float4 v = *(const float4*)(krow + u);
                KPs[(d0 + u + 0) * 68 + r] = v.x;
                KPs[(d0 + u + 1) * 68 + r] = v.y;
                KPs[(d0 + u + 2) * 68 + r] = v.z;
                KPs[(d0 + u + 3) * 68 + r] = v.w;
            }
            const float* vrow = vgbase + ((size_t)(c + r) * BATCH + b) * QKV_OUT + d0;
            #pragma unroll
            for (int u = 0; u < 16; u += 4)
                *(float4*)&Vs[r * 68 + d0 + u] = *(const float4*)(vrow + u);
        }
        __syncthreads();

        float acc[4][4] = {};
        #pragma unroll 8
        for (int d = 0; d < 64; ++d) {
            float4 av = *(const float4*)&Qs[d * 68 + (ty << 2)];
            float4 bv = *(const float4*)&KPs[d * 68 + (tx << 2)];
            float a4[4] = {av.x, av.y, av.z, av.w};
            float b4[4] = {bv.x, bv.y, bv.z, bv.w};
            #pragma unroll
            for (int i = 0; i < 4; ++i)
                #pragma unroll
                for (int j = 0; j < 4; ++j)
                    acc[i][j] = fmaf(a4[i], b4[j], acc[i][j]);
        }
        if (c == q0) {
            #pragma unroll
            for (int i = 0; i < 4; ++i) {
                int q = q0 + (ty << 2) + i;
                #pragma unroll
                for (int j = 0; j < 4; ++j)
                    if (c + (tx << 2) + j > q) acc[i][j] = -INFINITY;
            }
        }
        __syncthreads();

        #pragma unroll
        for (int i = 0; i < 4; ++i) {
            float rm = fmaxf(fmaxf(acc[i][0], acc[i][1]), fmaxf(acc[i][2], acc[i][3]));
            #pragma unroll
            for (int off = 8; off; off >>= 1) rm = fmaxf(rm, __shfl_xor(rm, off));
            float mn = fmaxf(m[i], rm);
            float corr = __expf(m[i] - mn);
            float ps = 0.f;
            #pragma unroll
            for (int j = 0; j < 4; ++j) { float p = __expf(acc[i][j] - mn); acc[i][j] = p; ps += p; }
            #pragma unroll
            for (int off = 8; off; off >>= 1) ps += __shfl_xor(ps, off);
            l[i] = l[i] * corr + ps;
            m[i] = mn;
            #pragma unroll
            for (int j = 0; j < 4; ++j) o[i][j] *= corr;
            #pragma unroll
            for (int j = 0; j < 4; ++j)
                KPs[((tx << 2) + j) * 68 + (ty << 2) + i] = acc[i][j];
        }
        __syncthreads();

        #pragma unroll 8
        for (int k = 0; k < 64; ++k) {
            float4 av = *(const float4*)&KPs[k * 68 + (ty << 2)];
            float4 bv = *(const float4*)&Vs[k * 68 + (tx << 2)];
            float a4[4] = {av.x, av.y, av.z, av.w};
            float b4[4] = {bv.x, bv.y, bv.z, bv.w};
            #pragma unroll
            for (int i = 0; i < 4; ++i)
                #pragma unroll
                for (int j = 0; j < 4; ++j)
                    o[i][j] = fmaf(a4[i], b4[j], o[i][j]);
        }
    }

    #pragma unroll
    for (int i = 0; i < 4; ++i) {
        int q = q0 + (ty << 2) + i;
        float inv = 1.f / l[i];
        float4 v = make_float4(o[i][0] * inv, o[i][1] * inv, o[i][2] * inv, o[i][3] * inv);
        *(float4*)(attn_out + ((size_t)q * BATCH + b) * HDIM + h * HD + (tx << 2)) = v;
    }
}

// ---------------- router: one wave per token, logits->softmax->top2 ----------------
__global__ __launch_bounds__(256) void router_kernel(const float* __restrict__ ln2,
                                                     const float* __restrict__ rw,
                                                     int* __restrict__ exp_idx,
                                                     float* __restrict__ gate) {
    int lane = threadIdx.x & 63;
    int w = threadIdx.x >> 6;
    int t = (blockIdx.x << 2) + w;
    float xr[16];
    #pragma unroll
    for (int i = 0; i < 16; ++i) xr[i] = ln2[(size_t)t * HDIM + i * 64 + lane];
    float lg[16];
    for (int e = 0; e < 16; ++e) {
        float a = 0.f;
        #pragma unroll
        for (int i = 0; i < 16; ++i) a = fmaf(xr[i], rw[e * HDIM + i * 64 + lane], a);
        #pragma unroll
        for (int off = 32; off; off >>= 1) a += __shfl_xor(a, off);
        lg[e] = a;
    }
    float mx = lg[0];
    #pragma unroll
    for (int e = 1; e < 16; ++e) mx = fmaxf(mx, lg[e]);
    float sum = 0.f;
    #pragma unroll
    for (int e = 0; e < 16; ++e) { lg[e] = expf(lg[e] - mx); sum += lg[e]; }
    float inv = 1.f / sum;
    int i1 = 0; float p1 = lg[0];
    #pragma unroll
    for (int e = 1; e < 16; ++e) if (lg[e] > p1) { p1 = lg[e]; i1 = e; }
    int i2 = -1; float p2 = -1.f;
    #pragma unroll
    for (int e = 0; e < 16; ++e) if (e != i1 && lg[e] > p2) { p2 = lg[e]; i2 = e; }
    if (lane == 0) {
        exp_idx[t * 2]     = i1;
        exp_idx[t * 2 + 1] = i2;
        gate[t * 2]        = p1 * inv;
        gate[t * 2 + 1]    = p2 * inv;
    }
}

// ---------------- slot-ordered capacity scan (single block) ----------------
__global__ __launch_bounds__(256) void scan_kernel(const int* __restrict__ exp_idx,
                                                   int* __restrict__ pos) {
    __shared__ int cnt[256][16];
    int tid = threadIdx.x;
    int c[16];
    #pragma unroll
    for (int e = 0; e < 16; ++e) c[e] = 0;
    int s0 = tid * 32;
    for (int i = 0; i < 32; ++i) {
        int ex = exp_idx[s0 + i];
        #pragma unroll
        for (int e = 0; e < 16; ++e) c[e] += (ex == e);
    }
    #pragma unroll
    for (int e = 0; e < 16; ++e) cnt[tid][e] = c[e];
    __syncthreads();
    if (tid < 16) {
        int run = 0;
        for (int i = 0; i < 256; ++i) { int t = cnt[i][tid]; cnt[i][tid] = run; run += t; }
    }
    __syncthreads();
    int off[16];
    #pragma unroll
    for (int e = 0; e < 16; ++e) off[e] = cnt[tid][e];
    for (int i = 0; i < 32; ++i) {
        int ex = exp_idx[s0 + i];
        #pragma unroll
        for (int e = 0; e < 16; ++e) if (ex == e) { pos[s0 + i] = off[e]; off[e]++; }
    }
}

// ---------------- scatter kept tokens into expert buffers ----------------
__global__ __launch_bounds__(256) void scatter_kernel(const float* __restrict__ ln2,
                                                      const int* __restrict__ exp_idx,
                                                      const int* __restrict__ pos,
                                                      float* __restrict__ buf) {
    int s = blockIdx.x;
    int p = pos[s];
    if (p >= CAP) return;
    int e = exp_idx[s];
    int tok = s >> 1;
    const float4* src = (const float4*)(ln2 + (size_t)tok * HDIM);
    float4* dst = (float4*)(buf + ((size_t)e * CAP1 + p) * HDIM);
    dst[threadIdx.x] = src[threadIdx.x];
}

// ---------------- combine: out = ha + sum_k gate*h2 (in-place on d_out) ----------------
__global__ __launch_bounds__(256) void combine_kernel(const float* __restrict__ h2,
                                                      const int* __restrict__ exp_idx,
                                                      const int* __restrict__ pos,
                                                      const float* __restrict__ gate,
                                                      float* __restrict__ out) {
    int t = blockIdx.x;
    int tid = threadIdx.x;
    float4 v = ((const float4*)(out + (size_t)t * HDIM))[tid];
    #pragma unroll
    for (int k = 0; k < 2; ++k) {
        int s = t * 2 + k;
        int p = pos[s];
        if (p < CAP) {
            float g = gate[s];
            float4 hv = ((const float4*)(h2 + ((size_t)exp_idx[s] * CAP1 + p) * HDIM))[tid];
            v.x = fmaf(g, hv.x, v.x); v.y = fmaf(g, hv.y, v.y);
            v.z = fmaf(g, hv.z, v.z); v.w = fmaf(g, hv.w, v.w);
        }
    }
    ((float4*)(out + (size_t)t * HDIM))[tid] = v;
}

extern "C" void kernel_launch(void* const* d_in, const int* in_sizes, int n_in,
                              void* d_out, int out_size, void* d_ws, size_t ws_size,
                              hipStream_t stream) {
    const float* hidden  = (const float*)d_in[0];
    const float* ln1w    = (const float*)d_in[1];
    const float* ln1b    = (const float*)d_in[2];
    const float* ln2w    = (const float*)d_in[3];
    const float* ln2b    = (const float*)d_in[4];
    const float* qkvw    = (const float*)d_in[5];
    const float* projw   = (const float*)d_in[6];
    const float* routerw = (const float*)d_in[7];
    const float* w1      = (const float*)d_in[8];
    const float* w2      = (const float*)d_in[9];

    float* ws      = (float*)d_ws;
    int*   exp_idx = (int*)(ws + OFF_SMALL);
    int*   pos     = exp_idx + NSLOT;
    float* gate    = (float*)(pos + NSLOT);
    float* bufA    = ws + OFF_A;     // ln1 out -> attn out -> ln2 out
    float* bufB    = ws + OFF_B;     // qkv (first 24MB) -> expert buf -> h2
    float* h1      = ws + OFF_C;     // full or chunked
    float* ha      = (float*)d_out;  // hidden_after_attn lives in d_out
    float* out     = (float*)d_out;

    // 1. LN1
    ln_kernel<<<TOKENS, 256, 0, stream>>>(hidden, ln1w, ln1b, bufA);
    // 2. QKV projection (split-bf16 MFMA)
    gemm_mfma<<<dim3(QKV_OUT / 128, TOKENS / 128, 1), 256, 0, stream>>>(
        bufA, qkvw, bufB, nullptr, TOKENS, QKV_OUT, HDIM, 0, 0, 0, 0);
    // 3. tiled causal GQA attention (overwrites A; ln1 dead)
    attn_tile_kernel<<<(S_LEN / 64) * BATCH * NH, 256, 0, stream>>>(bufB, bufA);
    // 4. output projection + residual -> hidden_after_attn (in d_out)
    gemm_mfma<<<dim3(HDIM / 128, TOKENS / 128, 1), 256, 0, stream>>>(
        bufA, projw, ha, hidden, TOKENS, HDIM, HDIM, 0, 0, 0, 0);
    // 5. LN2 (overwrites A; attn dead)
    ln_kernel<<<TOKENS, 256, 0, stream>>>(ha, ln2w, ln2b, bufA);
    // 6. router
    router_kernel<<<TOKENS / 4, 256, 0, stream>>>(bufA, routerw, exp_idx, gate);
    // 7. capacity positions
    scan_kernel<<<1, 256, 0, stream>>>(exp_idx, pos);
    // 8. scatter into expert buffers (overwrites qkv in B; dead)
    scatter_kernel<<<NSLOT, 256, 0, stream>>>(bufA, exp_idx, pos, bufB);

    // 9/10. expert FC1+gelu, FC2 (path fixed by ws_size — graph-capture safe)
    if (ws_size >= FLOATS_BIG * sizeof(float)) {
        gemm_mfma<<<dim3(FFN_D / 128, (CAP1 + 127) / 128, NE), 256, 0, stream>>>(
            bufB, w1, h1, nullptr, CAP1, FFN_D, HDIM,
            (long long)CAP1 * HDIM, (long long)FFN_D * HDIM, (long long)CAP1 * FFN_D, 1);
        gemm_mfma<<<dim3(HDIM / 128, (CAP1 + 127) / 128, NE), 256, 0, stream>>>(
            h1, w2, bufB, nullptr, CAP1, HDIM, FFN_D,
            (long long)CAP1 * FFN_D, (long long)HDIM * FFN_D, (long long)CAP1 * HDIM, 0);
    } else {
        for (int c0 = 0; c0 < CAP1; c0 += CHUNK) {
            int rows = (CAP1 - c0 < CHUNK) ? (CAP1 - c0) : CHUNK;
            gemm_mfma<<<dim3(FFN_D / 128, 1, NE), 256, 0, stream>>>(
                bufB + (size_t)c0 * HDIM, w1, h1, nullptr, rows, FFN_D, HDIM,
                (long long)CAP1 * HDIM, (long long)FFN_D * HDIM, (long long)CHUNK * FFN_D, 1);
            gemm_mfma<<<dim3(HDIM / 128, 1, NE), 256, 0, stream>>>(
                h1, w2, bufB + (size_t)c0 * HDIM, nullptr, rows, HDIM, FFN_D,
                (long long)CHUNK * FFN_D, (long long)HDIM * FFN_D, (long long)CAP1 * HDIM, 0);
        }
    }
    // 11. gated combine + residual
    combine_kernel<<<TOKENS, 256, 0, stream>>>(bufB, exp_idx, pos, gate, out);
}

// Round 3
// 927.935 us; speedup vs baseline: 2.4619x; 1.3196x over previous
//
#include <hip/hip_runtime.h>
#include <math.h>

// ---------------- problem constants ----------------
#define S_LEN   2048
#define BATCH   2
#define HDIM    1024
#define NH      16
#define NKV     4
#define HD      64
#define NE      16
#define FFN_D   2048
#define TOKENS  4096        // S*B
#define QKV_OUT 1536        // (NH + 2*NKV)*HD
#define CAP     640         // ceil(TOKENS*2/16*1.25)
#define CAP1    641
#define NSLOT   8192        // TOKENS*2
#define CHUNK   64          // MoE capacity-row chunk (small-ws path)

// ---------------- workspace layout (float elements) ----------------
#define OFF_SMALL 0UL                 // 24,576 floats: exp_idx, pos (int), gate
#define OFF_A     24576UL             // 4,194,304  (16 MB)
#define OFF_B     4218880UL           // 10,502,144 (40 MB); first 6,291,456 = qkv
#define OFF_C     14721024UL          // h1: full 21,004,288 (84 MB) or chunked 2,097,152 (8 MB)
#define FLOATS_BIG   35725312UL
#define FLOATS_SMALL 16818176UL

typedef __attribute__((ext_vector_type(8))) __bf16 bf16x8;
typedef __attribute__((ext_vector_type(4))) float f32x4;

__device__ __forceinline__ float gelu_tanh(float x) {
    float x3 = x * x * x;
    return 0.5f * x * (1.0f + tanhf(0.7978845608028654f * (x + 0.044715f * x3)));
}

// split fp32 -> (hi, lo) bf16 pair by truncation; x = hi + lo + O(2^-16 |x|)
__device__ __forceinline__ void split4(float4 v, ushort4& h, ushort4& l) {
    unsigned ux = __float_as_uint(v.x), uy = __float_as_uint(v.y);
    unsigned uz = __float_as_uint(v.z), uw = __float_as_uint(v.w);
    h = make_ushort4((unsigned short)(ux >> 16), (unsigned short)(uy >> 16),
                     (unsigned short)(uz >> 16), (unsigned short)(uw >> 16));
    float dx = v.x - __uint_as_float(ux & 0xFFFF0000u);
    float dy = v.y - __uint_as_float(uy & 0xFFFF0000u);
    float dz = v.z - __uint_as_float(uz & 0xFFFF0000u);
    float dw = v.w - __uint_as_float(uw & 0xFFFF0000u);
    l = make_ushort4((unsigned short)(__float_as_uint(dx) >> 16),
                     (unsigned short)(__float_as_uint(dy) >> 16),
                     (unsigned short)(__float_as_uint(dz) >> 16),
                     (unsigned short)(__float_as_uint(dw) >> 16));
}

__device__ __forceinline__ void split1(float v, unsigned short& h, unsigned short& l) {
    unsigned u = __float_as_uint(v);
    h = (unsigned short)(u >> 16);
    float d = v - __uint_as_float(u & 0xFFFF0000u);
    l = (unsigned short)(__float_as_uint(d) >> 16);
}

// ---------------- LayerNorm: one block per token row ----------------
__global__ __launch_bounds__(256) void ln_kernel(const float* __restrict__ x,
                                                 const float* __restrict__ w,
                                                 const float* __restrict__ b,
                                                 float* __restrict__ y) {
    int row = blockIdx.x;
    int tid = threadIdx.x;
    const float4* xr = (const float4*)(x + (size_t)row * HDIM);
    float4 v = xr[tid];
    float sum = v.x + v.y + v.z + v.w;
    float sq  = v.x*v.x + v.y*v.y + v.z*v.z + v.w*v.w;
    __shared__ float s1[256], s2[256];
    s1[tid] = sum; s2[tid] = sq;
    __syncthreads();
    for (int off = 128; off > 0; off >>= 1) {
        if (tid < off) { s1[tid] += s1[tid + off]; s2[tid] += s2[tid + off]; }
        __syncthreads();
    }
    float mu  = s1[0] * (1.0f / HDIM);
    float var = s2[0] * (1.0f / HDIM) - mu * mu;
    float rs  = rsqrtf(var + 1e-5f);
    float4 w4 = ((const float4*)w)[tid];
    float4 b4 = ((const float4*)b)[tid];
    float4 o;
    o.x = (v.x - mu) * rs * w4.x + b4.x;
    o.y = (v.y - mu) * rs * w4.y + b4.y;
    o.z = (v.z - mu) * rs * w4.z + b4.z;
    o.w = (v.w - mu) * rs * w4.w + b4.w;
    ((float4*)(y + (size_t)row * HDIM))[tid] = o;
}

// ---------------- MFMA split-bf16 GEMM: C[z] = A[z] @ B[z]^T ----------------
#define BM  128
#define BN  128
#define BK  32
#define PAD 8
#define LDK (BK + PAD)   // 40 bf16 = 80 B per row (16B-aligned)

__global__ __launch_bounds__(256) void gemm_mfma(const float* __restrict__ A,
                                                 const float* __restrict__ B,
                                                 float* __restrict__ C,
                                                 const float* __restrict__ resid,
                                                 int M, int N, int K,
                                                 long long sA, long long sB, long long sC,
                                                 int act) {
    __shared__ __align__(16) unsigned short Ah[BM * LDK];
    __shared__ __align__(16) unsigned short Al[BM * LDK];
    __shared__ __align__(16) unsigned short Bh[BN * LDK];
    __shared__ __align__(16) unsigned short Bl[BN * LDK];

    int z = blockIdx.z;
    const float* Ab = A + (long long)z * sA;
    const float* Bb = B + (long long)z * sB;
    float* Cb = C + (long long)z * sC;
    int bm = blockIdx.y << 7;
    int bn = blockIdx.x << 7;

    int t    = threadIdx.x;
    int lane = t & 63;
    int w    = t >> 6;
    int sr = t >> 3;          // 0..31
    int sc = (t & 7) << 2;    // fp32 col 0,4,...,28
    int fr = lane & 15;
    int fo = lane >> 4;       // 0..3
    int k0 = fo << 3;         // bf16 k-offset 0,8,16,24
    int wr = (w >> 1) << 6;   // wave row quadrant 0/64
    int wc = (w & 1) << 6;    // wave col quadrant 0/64

    f32x4 acc[4][4];
    #pragma unroll
    for (int m = 0; m < 4; ++m)
        #pragma unroll
        for (int n = 0; n < 4; ++n)
            acc[m][n] = (f32x4){0.f, 0.f, 0.f, 0.f};

    float4 ra[4], rb[4];
    #pragma unroll
    for (int p = 0; p < 4; ++p) {
        int arow = bm + (p << 5) + sr; if (arow > M - 1) arow = M - 1;
        ra[p] = *(const float4*)(Ab + (long long)arow * K + sc);
        rb[p] = *(const float4*)(Bb + (long long)(bn + (p << 5) + sr) * K + sc);
    }

    for (int kt = 0; kt < K; kt += BK) {
        __syncthreads();
        #pragma unroll
        for (int p = 0; p < 4; ++p) {
            int r = (p << 5) + sr;
            ushort4 h, l;
            split4(ra[p], h, l);
            *(ushort4*)&Ah[r * LDK + sc] = h;
            *(ushort4*)&Al[r * LDK + sc] = l;
            split4(rb[p], h, l);
            *(ushort4*)&Bh[r * LDK + sc] = h;
            *(ushort4*)&Bl[r * LDK + sc] = l;
        }
        __syncthreads();

        if (kt + BK < K) {
            int kn = kt + BK;
            #pragma unroll
            for (int p = 0; p < 4; ++p) {
                int arow = bm + (p << 5) + sr; if (arow > M - 1) arow = M - 1;
                ra[p] = *(const float4*)(Ab + (long long)arow * K + kn + sc);
                rb[p] = *(const float4*)(Bb + (long long)(bn + (p << 5) + sr) * K + kn + sc);
            }
        }

        bf16x8 ahf[4], alf[4];
        #pragma unroll
        for (int m = 0; m < 4; ++m) {
            int ro = (wr + (m << 4) + fr) * LDK + k0;
            ahf[m] = *reinterpret_cast<const bf16x8*>(&Ah[ro]);
            alf[m] = *reinterpret_cast<const bf16x8*>(&Al[ro]);
        }
        #pragma unroll
        for (int n = 0; n < 4; ++n) {
            int ro = (wc + (n << 4) + fr) * LDK + k0;
            bf16x8 bhf = *reinterpret_cast<const bf16x8*>(&Bh[ro]);
            bf16x8 blf = *reinterpret_cast<const bf16x8*>(&Bl[ro]);
            #pragma unroll
            for (int m = 0; m < 4; ++m) {
                acc[m][n] = __builtin_amdgcn_mfma_f32_16x16x32_bf16(ahf[m], bhf, acc[m][n], 0, 0, 0);
                acc[m][n] = __builtin_amdgcn_mfma_f32_16x16x32_bf16(alf[m], bhf, acc[m][n], 0, 0, 0);
                acc[m][n] = __builtin_amdgcn_mfma_f32_16x16x32_bf16(ahf[m], blf, acc[m][n], 0, 0, 0);
            }
        }
    }

    #pragma unroll
    for (int m = 0; m < 4; ++m) {
        int row0 = bm + wr + (m << 4) + (fo << 2);
        #pragma unroll
        for (int r = 0; r < 4; ++r) {
            int row = row0 + r;
            if (row >= M) continue;
            #pragma unroll
            for (int n = 0; n < 4; ++n) {
                float val = acc[m][n][r];
                if (act == 1) val = gelu_tanh(val);
                int col = bn + wc + (n << 4) + fr;
                long long off = (long long)row * N + col;
                if (resid) val += resid[(long long)z * sC + off];
                Cb[off] = val;
            }
        }
    }
}

// ---------------- MFMA split-bf16 causal GQA flash attention ----------------
// One 256-thread block (4 waves) per (64-q-tile, b, h). Wave w owns q-rows
// [16w,16w+16) and computes 1x4 fragments of mfma_f32_16x16x32_bf16, so each
// q-row's 64 scores live in one 16-lane group (softmax reduce = 4 shfl_xor).
// Q/K split hi/lo bf16 in LDS (3-MFMA fp32-accurate product); P split and
// reuses the K buffers; V staged transposed [d][k] with XOR-16 swizzle on k
// (keyed on d>>4): self-inverse, leaves low 3 addr bits untouched so b128
// reads stay aligned and recover contiguous k.
#define ALD 72   // LDS row stride in shorts (64 + 8 pad), 144 B, 16B-aligned

__global__ __launch_bounds__(256) void attn_mfma_kernel(const float* __restrict__ qkv,
                                                        float* __restrict__ attn_out) {
    int bid = blockIdx.x;
    int h   = bid & 15;
    int b   = (bid >> 4) & 1;
    int qt  = 31 - (bid >> 5);      // longest-first for tail balance
    int q0  = qt << 6;
    int kvh = h >> 2;
    int t   = threadIdx.x;
    int lane = t & 63;
    int w    = t >> 6;

    __shared__ __align__(16) unsigned short Qh[64 * ALD], Ql[64 * ALD];
    __shared__ __align__(16) unsigned short Kh[64 * ALD], Kl[64 * ALD];  // -> P after scores
    __shared__ __align__(16) unsigned short Vh[64 * ALD], Vl[64 * ALD];  // [d][k^swz]

    int sr = t >> 2;          // staging row 0..63
    int sd = (t & 3) << 4;    // staging dim 0,16,32,48

    // stage Q once (scaled by 1/sqrt(64), split)
    {
        const float* qrow = qkv + ((size_t)(q0 + sr) * BATCH + b) * QKV_OUT + h * HD + sd;
        #pragma unroll
        for (int u = 0; u < 16; u += 4) {
            float4 v = *(const float4*)(qrow + u);
            v.x *= 0.125f; v.y *= 0.125f; v.z *= 0.125f; v.w *= 0.125f;
            ushort4 hh, ll; split4(v, hh, ll);
            *(ushort4*)&Qh[sr * ALD + sd + u] = hh;
            *(ushort4*)&Ql[sr * ALD + sd + u] = ll;
        }
    }

    int fr = lane & 15;       // fragment col (k or d); also A-row for A-operand
    int fg = lane >> 4;       // 0..3
    int k8 = fg << 3;         // contraction sub-offset

    f32x4 o[4];
    float m[4], l[4];
    #pragma unroll
    for (int r = 0; r < 4; ++r) { m[r] = -INFINITY; l[r] = 0.f; }
    #pragma unroll
    for (int n = 0; n < 4; ++n) o[n] = (f32x4){0.f, 0.f, 0.f, 0.f};

    const float* kg = qkv + 1024 + kvh * HD;
    const float* vg = qkv + 1280 + kvh * HD;

    for (int c = 0; c <= q0; c += 64) {
        __syncthreads();   // prior PV reads (P in Kh/Kl, V) complete before restage
        {
            const float* krow = kg + ((size_t)(c + sr) * BATCH + b) * QKV_OUT + sd;
            #pragma unroll
            for (int u = 0; u < 16; u += 4) {
                float4 v = *(const float4*)(krow + u);
                ushort4 hh, ll; split4(v, hh, ll);
                *(ushort4*)&Kh[sr * ALD + sd + u] = hh;
                *(ushort4*)&Kl[sr * ALD + sd + u] = ll;
            }
            const float* vrow = vg + ((size_t)(c + sr) * BATCH + b) * QKV_OUT + sd;
            #pragma unroll
            for (int u = 0; u < 16; u += 4) {
                float4 v4 = *(const float4*)(vrow + u);
                float vv[4] = {v4.x, v4.y, v4.z, v4.w};
                #pragma unroll
                for (int e = 0; e < 4; ++e) {
                    int d = sd + u + e;
                    int kk = sr ^ (((d >> 4) & 3) << 4);   // conflict-free transpose
                    unsigned short hh, ll; split1(vv[e], hh, ll);
                    Vh[d * ALD + kk] = hh;
                    Vl[d * ALD + kk] = ll;
                }
            }
        }
        __syncthreads();

        // ---- scores: S[16w..16w+16)[0..64) = Q.K^T (contraction over d) ----
        f32x4 s[4];
        #pragma unroll
        for (int n = 0; n < 4; ++n) s[n] = (f32x4){0.f, 0.f, 0.f, 0.f};
        #pragma unroll
        for (int ks = 0; ks < 2; ++ks) {
            int koff = (ks << 5) + k8;
            bf16x8 qh = *(const bf16x8*)&Qh[((w << 4) + fr) * ALD + koff];
            bf16x8 ql = *(const bf16x8*)&Ql[((w << 4) + fr) * ALD + koff];
            #pragma unroll
            for (int n = 0; n < 4; ++n) {
                bf16x8 kh = *(const bf16x8*)&Kh[((n << 4) + fr) * ALD + koff];
                bf16x8 kl = *(const bf16x8*)&Kl[((n << 4) + fr) * ALD + koff];
                s[n] = __builtin_amdgcn_mfma_f32_16x16x32_bf16(qh, kh, s[n], 0, 0, 0);
                s[n] = __builtin_amdgcn_mfma_f32_16x16x32_bf16(ql, kh, s[n], 0, 0, 0);
                s[n] = __builtin_amdgcn_mfma_f32_16x16x32_bf16(qh, kl, s[n], 0, 0, 0);
            }
        }

        if (c == q0) {   // diagonal chunk: mask k > q (local indices, same base)
            #pragma unroll
            for (int n = 0; n < 4; ++n) {
                int kcol = (n << 4) + fr;
                #pragma unroll
                for (int r = 0; r < 4; ++r) {
                    int qrow = (w << 4) + (fg << 2) + r;
                    if (kcol > qrow) s[n][r] = -INFINITY;
                }
            }
        }

        // ---- online softmax: row = (fg<<2)+r within wave band ----
        #pragma unroll
        for (int r = 0; r < 4; ++r) {
            float rm = fmaxf(fmaxf(s[0][r], s[1][r]), fmaxf(s[2][r], s[3][r]));
            #pragma unroll
            for (int off = 8; off; off >>= 1) rm = fmaxf(rm, __shfl_xor(rm, off));
            float mn = fmaxf(m[r], rm);
            float corr = __expf(m[r] - mn);
            float ps = 0.f;
            #pragma unroll
            for (int n = 0; n < 4; ++n) { float p = __expf(s[n][r] - mn); s[n][r] = p; ps += p; }
            #pragma unroll
            for (int off = 8; off; off >>= 1) ps += __shfl_xor(ps, off);
            l[r] = l[r] * corr + ps;
            m[r] = mn;
            #pragma unroll
            for (int n = 0; n < 4; ++n) o[n][r] *= corr;
        }

        __syncthreads();   // all K reads done before P overwrites Kh/Kl

        #pragma unroll
        for (int n = 0; n < 4; ++n)
            #pragma unroll
            for (int r = 0; r < 4; ++r) {
                unsigned short ph, pl; split1(s[n][r], ph, pl);
                int qrow = (w << 4) + (fg << 2) + r;
                int kcol = (n << 4) + fr;
                Kh[qrow * ALD + kcol] = ph;
                Kl[qrow * ALD + kcol] = pl;
            }
        __syncthreads();

        // ---- O += P.V (contraction over k) ----
        #pragma unroll
        for (int ks = 0; ks < 2; ++ks) {
            int koff = (ks << 5) + k8;
            bf16x8 ph = *(const bf16x8*)&Kh[((w << 4) + fr) * ALD + koff];
            bf16x8 pl = *(const bf16x8*)&Kl[((w << 4) + fr) * ALD + koff];
            #pragma unroll
            for (int n = 0; n < 4; ++n) {
                int d = (n << 4) + fr;
                int kk = koff ^ (((d >> 4) & 3) << 4);
                bf16x8 vh = *(const bf16x8*)&Vh[d * ALD + kk];
                bf16x8 vl = *(const bf16x8*)&Vl[d * ALD + kk];
                o[n] = __builtin_amdgcn_mfma_f32_16x16x32_bf16(ph, vh, o[n], 0, 0, 0);
                o[n] = __builtin_amdgcn_mfma_f32_16x16x32_bf16(pl, vh, o[n], 0, 0, 0);
                o[n] = __builtin_amdgcn_mfma_f32_16x16x32_bf16(ph, vl, o[n], 0, 0, 0);
            }
        }
    }

    #pragma unroll
    for (int r = 0; r < 4; ++r) {
        int q = q0 + (w << 4) + (fg << 2) + r;
        float inv = 1.f / l[r];
        #pragma unroll
        for (int n = 0; n < 4; ++n)
            attn_out[((size_t)q * BATCH + b) * HDIM + h * HD + (n << 4) + fr] = o[n][r] * inv;
    }
}

// ---------------- router: one wave per token, logits->softmax->top2 ----------------
__global__ __launch_bounds__(256) void router_kernel(const float* __restrict__ ln2,
                                                     const float* __restrict__ rw,
                                                     int* __restrict__ exp_idx,
                                                     float* __restrict__ gate) {
    int lane = threadIdx.x & 63;
    int w = threadIdx.x >> 6;
    int t = (blockIdx.x << 2) + w;
    float xr[16];
    #pragma unroll
    for (int i = 0; i < 16; ++i) xr[i] = ln2[(size_t)t * HDIM + i * 64 + lane];
    float lg[16];
    for (int e = 0; e < 16; ++e) {
        float a = 0.f;
        #pragma unroll
        for (int i = 0; i < 16; ++i) a = fmaf(xr[i], rw[e * HDIM + i * 64 + lane], a);
        #pragma unroll
        for (int off = 32; off; off >>= 1) a += __shfl_xor(a, off);
        lg[e] = a;
    }
    float mx = lg[0];
    #pragma unroll
    for (int e = 1; e < 16; ++e) mx = fmaxf(mx, lg[e]);
    float sum = 0.f;
    #pragma unroll
    for (int e = 0; e < 16; ++e) { lg[e] = expf(lg[e] - mx); sum += lg[e]; }
    float inv = 1.f / sum;
    int i1 = 0; float p1 = lg[0];
    #pragma unroll
    for (int e = 1; e < 16; ++e) if (lg[e] > p1) { p1 = lg[e]; i1 = e; }
    int i2 = -1; float p2 = -1.f;
    #pragma unroll
    for (int e = 0; e < 16; ++e) if (e != i1 && lg[e] > p2) { p2 = lg[e]; i2 = e; }
    if (lane == 0) {
        exp_idx[t * 2]     = i1;
        exp_idx[t * 2 + 1] = i2;
        gate[t * 2]        = p1 * inv;
        gate[t * 2 + 1]    = p2 * inv;
    }
}

// ---------------- slot-ordered capacity scan (single block) ----------------
__global__ __launch_bounds__(256) void scan_kernel(const int* __restrict__ exp_idx,
                                                   int* __restrict__ pos) {
    __shared__ int cnt[256][16];
    int tid = threadIdx.x;
    int c[16];
    #pragma unroll
    for (int e = 0; e < 16; ++e) c[e] = 0;
    int s0 = tid * 32;
    for (int i = 0; i < 32; ++i) {
        int ex = exp_idx[s0 + i];
        #pragma unroll
        for (int e = 0; e < 16; ++e) c[e] += (ex == e);
    }
    #pragma unroll
    for (int e = 0; e < 16; ++e) cnt[tid][e] = c[e];
    __syncthreads();
    if (tid < 16) {
        int run = 0;
        for (int i = 0; i < 256; ++i) { int t = cnt[i][tid]; cnt[i][tid] = run; run += t; }
    }
    __syncthreads();
    int off[16];
    #pragma unroll
    for (int e = 0; e < 16; ++e) off[e] = cnt[tid][e];
    for (int i = 0; i < 32; ++i) {
        int ex = exp_idx[s0 + i];
        #pragma unroll
        for (int e = 0; e < 16; ++e) if (ex == e) { pos[s0 + i] = off[e]; off[e]++; }
    }
}

// ---------------- scatter kept tokens into expert buffers ----------------
__global__ __launch_bounds__(256) void scatter_kernel(const float* __restrict__ ln2,
                                                      const int* __restrict__ exp_idx,
                                                      const int* __restrict__ pos,
                                                      float* __restrict__ buf) {
    int s = blockIdx.x;
    int p = pos[s];
    if (p >= CAP) return;
    int e = exp_idx[s];
    int tok = s >> 1;
    const float4* src = (const float4*)(ln2 + (size_t)tok * HDIM);
    float4* dst = (float4*)(buf + ((size_t)e * CAP1 + p) * HDIM);
    dst[threadIdx.x] = src[threadIdx.x];
}

// ---------------- combine: out = ha + sum_k gate*h2 (in-place on d_out) ----------------
__global__ __launch_bounds__(256) void combine_kernel(const float* __restrict__ h2,
                                                      const int* __restrict__ exp_idx,
                                                      const int* __restrict__ pos,
                                                      const float* __restrict__ gate,
                                                      float* __restrict__ out) {
    int t = blockIdx.x;
    int tid = threadIdx.x;
    float4 v = ((const float4*)(out + (size_t)t * HDIM))[tid];
    #pragma unroll
    for (int k = 0; k < 2; ++k) {
        int s = t * 2 + k;
        int p = pos[s];
        if (p < CAP) {
            float g = gate[s];
            float4 hv = ((const float4*)(h2 + ((size_t)exp_idx[s] * CAP1 + p) * HDIM))[tid];
            v.x = fmaf(g, hv.x, v.x); v.y = fmaf(g, hv.y, v.y);
            v.z = fmaf(g, hv.z, v.z); v.w = fmaf(g, hv.w, v.w);
        }
    }
    ((float4*)(out + (size_t)t * HDIM))[tid] = v;
}

extern "C" void kernel_launch(void* const* d_in, const int* in_sizes, int n_in,
                              void* d_out, int out_size, void* d_ws, size_t ws_size,
                              hipStream_t stream) {
    const float* hidden  = (const float*)d_in[0];
    const float* ln1w    = (const float*)d_in[1];
    const float* ln1b    = (const float*)d_in[2];
    const float* ln2w    = (const float*)d_in[3];
    const float* ln2b    = (const float*)d_in[4];
    const float* qkvw    = (const float*)d_in[5];
    const float* projw   = (const float*)d_in[6];
    const float* routerw = (const float*)d_in[7];
    const float* w1      = (const float*)d_in[8];
    const float* w2      = (const float*)d_in[9];

    float* ws      = (float*)d_ws;
    int*   exp_idx = (int*)(ws + OFF_SMALL);
    int*   pos     = exp_idx + NSLOT;
    float* gate    = (float*)(pos + NSLOT);
    float* bufA    = ws + OFF_A;     // ln1 out -> attn out -> ln2 out
    float* bufB    = ws + OFF_B;     // qkv (first 24MB) -> expert buf -> h2
    float* h1      = ws + OFF_C;     // full or chunked
    float* ha      = (float*)d_out;  // hidden_after_attn lives in d_out
    float* out     = (float*)d_out;

    // 1. LN1
    ln_kernel<<<TOKENS, 256, 0, stream>>>(hidden, ln1w, ln1b, bufA);
    // 2. QKV projection (split-bf16 MFMA)
    gemm_mfma<<<dim3(QKV_OUT / 128, TOKENS / 128, 1), 256, 0, stream>>>(
        bufA, qkvw, bufB, nullptr, TOKENS, QKV_OUT, HDIM, 0, 0, 0, 0);
    // 3. MFMA causal GQA attention (overwrites A; ln1 dead)
    attn_mfma_kernel<<<(S_LEN / 64) * BATCH * NH, 256, 0, stream>>>(bufB, bufA);
    // 4. output projection + residual -> hidden_after_attn (in d_out)
    gemm_mfma<<<dim3(HDIM / 128, TOKENS / 128, 1), 256, 0, stream>>>(
        bufA, projw, ha, hidden, TOKENS, HDIM, HDIM, 0, 0, 0, 0);
    // 5. LN2 (overwrites A; attn dead)
    ln_kernel<<<TOKENS, 256, 0, stream>>>(ha, ln2w, ln2b, bufA);
    // 6. router
    router_kernel<<<TOKENS / 4, 256, 0, stream>>>(bufA, routerw, exp_idx, gate);
    // 7. capacity positions
    scan_kernel<<<1, 256, 0, stream>>>(exp_idx, pos);
    // 8. scatter into expert buffers (overwrites qkv in B; dead)
    scatter_kernel<<<NSLOT, 256, 0, stream>>>(bufA, exp_idx, pos, bufB);

    // 9/10. expert FC1+gelu, FC2 (path fixed by ws_size — graph-capture safe)
    if (ws_size >= FLOATS_BIG * sizeof(float)) {
        gemm_mfma<<<dim3(FFN_D / 128, (CAP1 + 127) / 128, NE), 256, 0, stream>>>(
            bufB, w1, h1, nullptr, CAP1, FFN_D, HDIM,
            (long long)CAP1 * HDIM, (long long)FFN_D * HDIM, (long long)CAP1 * FFN_D, 1);
        gemm_mfma<<<dim3(HDIM / 128, (CAP1 + 127) / 128, NE), 256, 0, stream>>>(
            h1, w2, bufB, nullptr, CAP1, HDIM, FFN_D,
            (long long)CAP1 * FFN_D, (long long)HDIM * FFN_D, (long long)CAP1 * HDIM, 0);
    } else {
        for (int c0 = 0; c0 < CAP1; c0 += CHUNK) {
            int rows = (CAP1 - c0 < CHUNK) ? (CAP1 - c0) : CHUNK;
            gemm_mfma<<<dim3(FFN_D / 128, 1, NE), 256, 0, stream>>>(
                bufB + (size_t)c0 * HDIM, w1, h1, nullptr, rows, FFN_D, HDIM,
                (long long)CAP1 * HDIM, (long long)FFN_D * HDIM, (long long)CHUNK * FFN_D, 1);
            gemm_mfma<<<dim3(HDIM / 128, 1, NE), 256, 0, stream>>>(
                h1, w2, bufB + (size_t)c0 * HDIM, nullptr, rows, HDIM, FFN_D,
                (long long)CHUNK * FFN_D, (long long)HDIM * FFN_D, (long long)CAP1 * HDIM, 0);
        }
    }
    // 11. gated combine + residual
    combine_kernel<<<TOKENS, 256, 0, stream>>>(bufB, exp_idx, pos, gate, out);
}